// Round 20
// baseline (178.228 us; speedup 1.0000x reference)
//
#include <hip/hip_runtime.h>

#define T_STEPS 16
#define H 64
#define S_IN 25
#define A_OUT 4
#define NB 65536
#define UPW 8             // units per thread (H / 8 waves)
#define WPB 8             // waves per block
#define EPB 256           // batch elements per block (FOUR per lane)

typedef unsigned long long ull;

__device__ __forceinline__ float fmaf_(float a, float b, float c) { return __builtin_fmaf(a, b, c); }

// W2 -> per-wave contiguous blocks W2G[wq][k][j] = W2[(wq*8+j)][k] (2 KB per
// wave, k-adjacent rows contiguous -> s_loads merge to dwordx16); W3 -> [h][a].
__global__ void snn_prep(const float* __restrict__ W2, const float* __restrict__ W3,
                         float* __restrict__ W2G, float* __restrict__ W3T) {
    int i = blockIdx.x * blockDim.x + threadIdx.x;
    if (i < H * H) {
        int wq = i >> 9, k = (i >> 3) & 63, j = i & 7;
        W2G[i] = W2[(wq * 8 + j) * 64 + k];
    }
    if (i < A_OUT * H) { int a = i >> 6, h = i & 63; W3T[h * A_OUT + a] = W3[a * H + h]; }
}

// E=4 scaling of the proven R15/R19 structure: 4 elems/lane, one uniform
// weight row feeds 32 FMAs (2x R19) -> per-FMA s_load exposure and per-CU
// scalar traffic halve; lost TLP (2 waves/SIMD, 1 block/CU, LDS 93 KB) is
// replaced by 4-chain ILP. Precomputed s1 shift-registers + f32 spike tile
// (R16+R15 techniques). Weights stay on the scalar s_load path.
__global__ __launch_bounds__(512, 2) void snn_main(
    const float* __restrict__ x,
    const float* __restrict__ W1, const float* __restrict__ b1,
    const float* __restrict__ W2G, const float* __restrict__ b2,
    const float* __restrict__ W3T, const float* __restrict__ b3,
    float* __restrict__ out, int* __restrict__ g_pre, int* __restrict__ g_post)
{
#pragma clang fp contract(off)
    __shared__ float s1f[H][EPB];                      // 64 KB: f32 spike tile (single)
    __shared__ float4 w3s[H];                          // 1 KB
    __shared__ unsigned int s2buf[2][WPB][EPB];        // 16 KB (double-buffered)
    __shared__ float m3acc[EPB][8];                    // 8 KB
    __shared__ int lds_pre[T_STEPS * H];               // 4 KB
    __shared__ int lds_post[T_STEPS * A_OUT];          // 256 B

    const int tid = threadIdx.x;
    if (tid < H) w3s[tid] = reinterpret_cast<const float4*>(W3T)[tid];
    for (int i = tid; i < T_STEPS * H; i += 512) lds_pre[i] = 0;
    if (tid < T_STEPS * A_OUT) lds_post[tid] = 0;
    for (int i = tid; i < EPB * 8; i += 512) (&m3acc[0][0])[i] = 0.0f;   // strided (R12 lesson)

    const int lane  = tid & 63;
    const int wq    = __builtin_amdgcn_readfirstlane(tid >> 6);  // wave 0..7 (SGPR)
    const int hbase = UPW * wq;
    const int b0    = blockIdx.x * EPB + lane;         // elements b0, +64, +128, +192

    // ---- prologue: cur1 (exact s-chain) + all-t m1 evolution for 4 elems,
    //      packing per-t 8-bit masks into u64 shift registers. ----
    ull msk0[4], msk1[4];
    {
        float cur1[4][UPW], m1[4][UPW];
        #pragma unroll
        for (int e = 0; e < 4; ++e) {
            float xv[S_IN];
            #pragma unroll
            for (int s = 0; s < S_IN; ++s) xv[s] = x[(b0 + 64 * e) * S_IN + s];
            #pragma unroll
            for (int j = 0; j < UPW; ++j) {
                int h = hbase + j;
                float acc = 0.0f;
                #pragma unroll
                for (int s = 0; s < S_IN; ++s) acc = fmaf_(xv[s], W1[h * S_IN + s], acc);
                cur1[e][j] = acc + b1[h];
                m1[e][j] = 0.0f;
            }
            msk0[e] = 0ull; msk1[e] = 0ull;
        }
        for (int t = 0; t < 8; ++t) {
            #pragma unroll
            for (int e = 0; e < 4; ++e) {
                unsigned int sm = 0u;
                #pragma unroll
                for (int j = 0; j < UPW; ++j) {
                    float m = 0.95f * m1[e][j]; m = m + cur1[e][j];
                    bool sp = m > 1.0f; m1[e][j] = sp ? (m - 1.0f) : m;
                    sm |= (sp ? 1u : 0u) << j;
                }
                msk0[e] |= ((ull)sm) << (8 * t);
            }
        }
        for (int t = 0; t < 8; ++t) {
            #pragma unroll
            for (int e = 0; e < 4; ++e) {
                unsigned int sm = 0u;
                #pragma unroll
                for (int j = 0; j < UPW; ++j) {
                    float m = 0.95f * m1[e][j]; m = m + cur1[e][j];
                    bool sp = m > 1.0f; m1[e][j] = sp ? (m - 1.0f) : m;
                    sm |= (sp ? 1u : 0u) << j;
                }
                msk1[e] |= ((ull)sm) << (8 * t);
            }
        }
    }

    // ---- write t=0 tile from shift-register low bytes ----
    #pragma unroll
    for (int e = 0; e < 4; ++e) {
        unsigned int u = (unsigned int)msk0[e] & 0xFFu;
        #pragma unroll
        for (int j = 0; j < UPW; ++j)
            s1f[hbase + j][lane + 64 * e] = ((u >> j) & 1u) ? 1.0f : 0.0f;
        msk0[e] = (msk0[e] >> 8) | (msk1[e] << 56); msk1[e] >>= 8;
    }

    float m2[4][UPW];
    #pragma unroll
    for (int e = 0; e < 4; ++e)
    #pragma unroll
    for (int j = 0; j < UPW; ++j) m2[e][j] = 0.0f;

    const float* wbase = W2G + wq * 512;               // wave's contiguous 2 KB block

    __syncthreads();                                   // tile(0) + staging complete

    for (int t = 0; t < T_STEPS; ++t) {
        const int slot = t & 1;

        #pragma unroll
        for (int e = 0; e < 4; ++e)
        #pragma unroll
        for (int j = 0; j < UPW; ++j) m2[e][j] = 0.95f * m2[e][j];

        // ---- layer 2: exact ascending-k chain; sf via stride-1 ds_read_b32;
        //      weights via wave-uniform s_load at base+imm (mergeable); 32 FMA/k.
        #pragma unroll 8
        for (int k = 0; k < H; ++k) {
            const float sf0 = s1f[k][lane];
            const float sf1 = s1f[k][lane + 64];
            const float sf2 = s1f[k][lane + 128];
            const float sf3 = s1f[k][lane + 192];
            const float* wr = wbase + k * 8;
            #pragma unroll
            for (int j = 0; j < UPW; ++j) {
                const float w = wr[j];
                m2[0][j] = fmaf_(sf0, w, m2[0][j]);
                m2[1][j] = fmaf_(sf1, w, m2[1][j]);
                m2[2][j] = fmaf_(sf2, w, m2[2][j]);
                m2[3][j] = fmaf_(sf3, w, m2[3][j]);
            }
        }

        // ---- layer-2 spikes + pre-counts (8 units x 256 elems via 4 ballots) ----
        int myCnt = 0;
        unsigned int s2m[4] = {0u, 0u, 0u, 0u};
        #pragma unroll
        for (int j = 0; j < UPW; ++j) {
            int cnt = 0;
            #pragma unroll
            for (int e = 0; e < 4; ++e) {
                float m = m2[e][j] + b2[hbase + j];
                bool sp = m > 1.0f;
                m2[e][j] = m - (sp ? 1.0f : 0.0f);
                s2m[e] |= (sp ? 1u : 0u) << j;
                cnt += (int)__popcll(__ballot(sp));
            }
            myCnt = (lane == j) ? cnt : myCnt;
        }
        #pragma unroll
        for (int e = 0; e < 4; ++e) s2buf[slot][wq][lane + 64 * e] = s2m[e];
        if (lane < UPW) lds_pre[t * H + hbase + lane] = myCnt;   // single writer per (t,h)

        __syncthreads();     // barrier 1: everyone done READING s1f(t)

        // ---- write tile for t+1 from shift registers (overwrite, single buf) ----
        if (t < T_STEPS - 1) {
            #pragma unroll
            for (int e = 0; e < 4; ++e) {
                unsigned int u = (unsigned int)msk0[e] & 0xFFu;
                #pragma unroll
                for (int j = 0; j < UPW; ++j)
                    s1f[hbase + j][lane + 64 * e] = ((u >> j) & 1u) ? 1.0f : 0.0f;
                msk0[e] = (msk0[e] >> 8) | (msk1[e] << 56); msk1[e] >>= 8;
            }
        }

        __syncthreads();     // barrier 2: tile(t+1) ready; s2buf(t) visible

        // ---- layer 3: 4 duty waves every other t (256 elems), exact h-chain ----
        if ((wq >> 2) == (t & 1)) {
            const int el = (wq & 3) * 64 + lane;
            unsigned int q0 = s2buf[slot][0][el], q1 = s2buf[slot][1][el];
            unsigned int q2 = s2buf[slot][2][el], q3 = s2buf[slot][3][el];
            unsigned int q4 = s2buf[slot][4][el], q5 = s2buf[slot][5][el];
            unsigned int q6 = s2buf[slot][6][el], q7 = s2buf[slot][7][el];
            ull s2v = (ull)(q0 | (q1 << 8) | (q2 << 16) | (q3 << 24))
                    | ((ull)(q4 | (q5 << 8) | (q6 << 16) | (q7 << 24)) << 32);
            float m3[A_OUT], ac[A_OUT];
            #pragma unroll
            for (int a = 0; a < A_OUT; ++a) { m3[a] = 0.95f * m3acc[el][a]; ac[a] = m3acc[el][4 + a]; }
            for (int h = 0; h < H; ++h) {        // h ascending: exact chain order
                float s2f = (float)((unsigned)s2v & 1u);
                s2v >>= 1;
                const float4 w = w3s[h];         // broadcast ds_read
                m3[0] = fmaf_(s2f, w.x, m3[0]);
                m3[1] = fmaf_(s2f, w.y, m3[1]);
                m3[2] = fmaf_(s2f, w.z, m3[2]);
                m3[3] = fmaf_(s2f, w.w, m3[3]);
            }
            int myPost = 0;
            #pragma unroll
            for (int a = 0; a < A_OUT; ++a) {
                float m = m3[a] + b3[a];
                bool sp = m > 1.0f;
                float s3f = sp ? 1.0f : 0.0f;
                m3[a] = m - s3f;
                ac[a] = ac[a] + s3f;
                int c = (int)__popcll(__ballot(sp));
                myPost = (lane == a) ? c : myPost;
            }
            if (lane < A_OUT) atomicAdd(&lds_post[t * A_OUT + lane], myPost);  // 4 duty waves
            if (t == T_STEPS - 1) {
                float r0 = ac[0] * 0.0625f, r1 = ac[1] * 0.0625f;
                float r2 = ac[2] * 0.0625f, r3 = ac[3] * 0.0625f;
                float mx = fmaxf(fmaxf(r0, r1), fmaxf(r2, r3));
                float e0 = expf(r0 - mx), e1 = expf(r1 - mx);
                float e2 = expf(r2 - mx), e3 = expf(r3 - mx);
                float s = ((e0 + e1) + e2) + e3;
                reinterpret_cast<float4*>(out)[blockIdx.x * EPB + el] =
                    make_float4(e0 / s, e1 / s, e2 / s, e3 / s);
            } else {
                #pragma unroll
                for (int a = 0; a < A_OUT; ++a) { m3acc[el][a] = m3[a]; m3acc[el][4 + a] = ac[a]; }
            }
        }
    }

    __syncthreads();
    for (int i = tid; i < T_STEPS * H; i += 512) atomicAdd(&g_pre[i], lds_pre[i]);
    if (tid < T_STEPS * A_OUT) atomicAdd(&g_post[tid], lds_post[tid]);
}

// elig_t = 0.95*elig_{t-1} + (A_PLUS-A_MINUS) * outer(post_t, pre_t); exact counts/B.
__global__ void snn_elig(const int* __restrict__ g_pre, const int* __restrict__ g_post,
                         const float* __restrict__ elig0, float* __restrict__ out) {
#pragma clang fp contract(off)
    int i = threadIdx.x;                 // 256 = A_OUT * H
    int a = i >> 6, h = i & 63;
    float e = elig0[i];
    const float invB = 1.0f / 65536.0f;
    for (int t = 0; t < T_STEPS; ++t) {
        float pre  = (float)g_pre[t * H + h] * invB;
        float post = (float)g_post[t * A_OUT + a] * invB;
        e = 0.95f * e + (-0.002f) * (post * pre);
    }
    out[NB * A_OUT + i] = e;
}

extern "C" void kernel_launch(void* const* d_in, const int* in_sizes, int n_in,
                              void* d_out, int out_size, void* d_ws, size_t ws_size,
                              hipStream_t stream) {
    const float* x     = (const float*)d_in[0];
    const float* W1    = (const float*)d_in[1];
    const float* b1    = (const float*)d_in[2];
    const float* W2    = (const float*)d_in[3];
    const float* b2    = (const float*)d_in[4];
    const float* W3    = (const float*)d_in[5];
    const float* b3    = (const float*)d_in[6];
    const float* elig0 = (const float*)d_in[7];
    float* out = (float*)d_out;

    char* ws = (char*)d_ws;
    int*   g_pre  = (int*)(ws);                    // 1024 ints
    int*   g_post = (int*)(ws + 4096);             // 64 ints
    float* W2G    = (float*)(ws + 8192);           // 4096 floats (per-wave blocks)
    float* W3T    = (float*)(ws + 8192 + 16384);   // 256 floats

    (void)hipMemsetAsync(ws, 0, 4096 + 256, stream);  // zero count accumulators every launch
    snn_prep<<<17, 256, 0, stream>>>(W2, W3, W2G, W3T);
    snn_main<<<NB / EPB, 512, 0, stream>>>(x, W1, b1, W2G, b2, W3T, b3, out, g_pre, g_post);
    snn_elig<<<1, 256, 0, stream>>>(g_pre, g_post, elig0, out);
}

// Round 21
// 156.023 us; speedup vs baseline: 1.1423x; 1.1423x over previous
//
#include <hip/hip_runtime.h>

#define T_STEPS 16
#define H 64
#define S_IN 25
#define A_OUT 4
#define NB 65536
#define UPW 8             // units per thread (H / 8 waves)
#define WPB 8             // waves per block
#define EPB 128           // batch elements per block (two per lane)

typedef unsigned long long ull;

__device__ __forceinline__ float fmaf_(float a, float b, float c) { return __builtin_fmaf(a, b, c); }

// Transpose W2 (64x64) and W3 (4x64) into workspace (row-major [k][h], [h][a]).
__global__ void snn_prep(const float* __restrict__ W2, const float* __restrict__ W3,
                         float* __restrict__ W2T, float* __restrict__ W3T) {
    int i = blockIdx.x * blockDim.x + threadIdx.x;
    if (i < H * H) { int h = i >> 6, k = i & 63; W2T[k * H + h] = W2[h * H + k]; }
    if (i < A_OUT * H) { int a = i >> 6, h = i & 63; W3T[h * A_OUT + a] = W3[a * H + h]; }
}

// BEST VERIFIED CONFIG (R15, 156.0us, absmax 0.0): E=2 (two elems/lane),
// 8 waves/block, 4 waves/SIMD; layer-1 spikes exchanged as f32 0/1 in a
// single-buffer LDS tile (k-loop select = stride-1 ds_read_b32, LDS pipe);
// weights on the wave-uniform scalar s_load path (each row feeds 16 FMAs);
// rotating duty waves for the exact ascending-h layer-3 chain.
// Optimum confirmed bilaterally: E=1 (186us), E=4 (178us), 8 waves (186us),
// 2 waves (178us), LDS weights (229-570us), bit-mask select (+25% VALU).
__global__ __launch_bounds__(512, 4) __attribute__((amdgpu_waves_per_eu(4, 4)))
void snn_main(
    const float* __restrict__ x,
    const float* __restrict__ W1, const float* __restrict__ b1,
    const float* __restrict__ W2T, const float* __restrict__ b2,
    const float* __restrict__ W3T, const float* __restrict__ b3,
    float* __restrict__ out, int* __restrict__ g_pre, int* __restrict__ g_post)
{
#pragma clang fp contract(off)
    __shared__ float s1f[H][EPB];               // 32 KB: s1 spikes as 0.0/1.0 (single buffer)
    __shared__ float4 w3s[H];                   // 1 KB: W3T rows, broadcast-read
    __shared__ unsigned int s2buf[2][WPB][EPB]; // 4 KB: s2 bit-masks (double-buffered)
    __shared__ float m3acc[EPB][8];             // 4 KB: [elem][0..3]=m3, [4..7]=acc
    __shared__ int lds_pre[T_STEPS * H];        // 4 KB
    __shared__ int lds_post[T_STEPS * A_OUT];   // 256 B

    const int tid = threadIdx.x;
    if (tid < H) w3s[tid] = reinterpret_cast<const float4*>(W3T)[tid];
    for (int i = tid; i < T_STEPS * H; i += 512) lds_pre[i] = 0;
    if (tid < T_STEPS * A_OUT) lds_post[tid] = 0;
    for (int i = tid; i < EPB * 8; i += 512) (&m3acc[0][0])[i] = 0.0f;   // strided (R12 lesson)

    const int lane  = tid & 63;
    const int wq    = __builtin_amdgcn_readfirstlane(tid >> 6);  // wave 0..7 (SGPR)
    const int hbase = UPW * wq;                                  // this wave's unit range
    const int bA    = blockIdx.x * EPB + lane;                   // element A
    const int bB    = bA + 64;                                   // element B

    // cur1 for both elements' 8 units (exact s-chain), one element at a time.
    float cur1A[UPW], cur1B[UPW];
    {
        float xv[S_IN];
        #pragma unroll
        for (int s = 0; s < S_IN; ++s) xv[s] = x[bA * S_IN + s];
        #pragma unroll
        for (int j = 0; j < UPW; ++j) {
            int h = hbase + j;
            float acc = 0.0f;
            #pragma unroll
            for (int s = 0; s < S_IN; ++s) acc = fmaf_(xv[s], W1[h * S_IN + s], acc);
            cur1A[j] = acc + b1[h];
        }
        #pragma unroll
        for (int s = 0; s < S_IN; ++s) xv[s] = x[bB * S_IN + s];
        #pragma unroll
        for (int j = 0; j < UPW; ++j) {
            int h = hbase + j;
            float acc = 0.0f;
            #pragma unroll
            for (int s = 0; s < S_IN; ++s) acc = fmaf_(xv[s], W1[h * S_IN + s], acc);
            cur1B[j] = acc + b1[h];
        }
    }

    float m1A[UPW], m1B[UPW], m2A[UPW], m2B[UPW];
    #pragma unroll
    for (int j = 0; j < UPW; ++j) { m1A[j] = 0.0f; m1B[j] = 0.0f; m2A[j] = 0.0f; m2B[j] = 0.0f; }

    __syncthreads();                            // staging + init done

    // ---- prologue: layer-1 at t=0, spikes as floats straight to s1f ----
    #pragma unroll
    for (int j = 0; j < UPW; ++j) {
        float ma = 0.95f * m1A[j]; ma = ma + cur1A[j];
        bool pa = ma > 1.0f; m1A[j] = pa ? (ma - 1.0f) : ma;
        s1f[hbase + j][lane] = pa ? 1.0f : 0.0f;
        float mb = 0.95f * m1B[j]; mb = mb + cur1B[j];
        bool pb = mb > 1.0f; m1B[j] = pb ? (mb - 1.0f) : mb;
        s1f[hbase + j][lane + 64] = pb ? 1.0f : 0.0f;
    }
    __syncthreads();

    for (int t = 0; t < T_STEPS; ++t) {
        const int slot = t & 1;

        #pragma unroll
        for (int j = 0; j < UPW; ++j) { m2A[j] = 0.95f * m2A[j]; m2B[j] = 0.95f * m2B[j]; }

        // ---- layer 2: exact ascending-k chain; sf via ds_read_b32 (stride-1,
        //      2-way = free), weights via wave-uniform s_load; 16 FMA/k. ----
        #pragma unroll 8
        for (int k = 0; k < H; ++k) {
            const float sfA = s1f[k][lane];
            const float sfB = s1f[k][lane + 64];
            const float* wr = W2T + k * H + hbase;
            #pragma unroll
            for (int j = 0; j < UPW; ++j) {
                const float w = wr[j];
                m2A[j] = fmaf_(sfA, w, m2A[j]);
                m2B[j] = fmaf_(sfB, w, m2B[j]);
            }
        }

        // ---- layer-2 spikes + pre-counts (8 units x 128 elems via 2 ballots) ----
        unsigned int s2A = 0u, s2B = 0u;
        int myCnt = 0;
        #pragma unroll
        for (int j = 0; j < UPW; ++j) {
            float ma = m2A[j] + b2[hbase + j];
            bool pa = ma > 1.0f;
            m2A[j] = ma - (pa ? 1.0f : 0.0f);
            s2A |= (pa ? 1u : 0u) << j;
            float mb = m2B[j] + b2[hbase + j];
            bool pb = mb > 1.0f;
            m2B[j] = mb - (pb ? 1.0f : 0.0f);
            s2B |= (pb ? 1u : 0u) << j;
            int cnt = (int)__popcll(__ballot(pa)) + (int)__popcll(__ballot(pb));
            myCnt = (lane == j) ? cnt : myCnt;
        }
        s2buf[slot][wq][lane] = s2A;
        s2buf[slot][wq][lane + 64] = s2B;
        if (lane < UPW) lds_pre[t * H + hbase + lane] = myCnt;   // single writer per (t,h)

        __syncthreads();     // barrier 1: everyone done READING s1f(t)

        // ---- layer 1 for t+1: overwrite s1f (single buffer) ----
        if (t < T_STEPS - 1) {
            #pragma unroll
            for (int j = 0; j < UPW; ++j) {
                float ma = 0.95f * m1A[j]; ma = ma + cur1A[j];
                bool pa = ma > 1.0f; m1A[j] = pa ? (ma - 1.0f) : ma;
                s1f[hbase + j][lane] = pa ? 1.0f : 0.0f;
                float mb = 0.95f * m1B[j]; mb = mb + cur1B[j];
                bool pb = mb > 1.0f; m1B[j] = pb ? (mb - 1.0f) : mb;
                s1f[hbase + j][lane + 64] = pb ? 1.0f : 0.0f;
            }
        }
        __syncthreads();     // barrier 2: s1f(t+1) complete; s2buf(t) visible

        // ---- layer 3: two rotating duty waves, 64 elems each, exact h-chain ----
        const int duty = wq & 3;
        if (duty == (t & 3)) {
            const int el = (wq < 4) ? lane : (lane + 64);        // elem handled by this lane
            unsigned int q0 = s2buf[slot][0][el], q1 = s2buf[slot][1][el];
            unsigned int q2 = s2buf[slot][2][el], q3 = s2buf[slot][3][el];
            unsigned int q4 = s2buf[slot][4][el], q5 = s2buf[slot][5][el];
            unsigned int q6 = s2buf[slot][6][el], q7 = s2buf[slot][7][el];
            ull s2v = (ull)(q0 | (q1 << 8) | (q2 << 16) | (q3 << 24))
                    | ((ull)(q4 | (q5 << 8) | (q6 << 16) | (q7 << 24)) << 32);
            float m3[A_OUT], ac[A_OUT];
            #pragma unroll
            for (int a = 0; a < A_OUT; ++a) { m3[a] = 0.95f * m3acc[el][a]; ac[a] = m3acc[el][4 + a]; }
            for (int h = 0; h < H; ++h) {        // h ascending: exact chain order
                float s2f = (float)((unsigned)s2v & 1u);
                s2v >>= 1;
                const float4 w = w3s[h];         // broadcast ds_read
                m3[0] = fmaf_(s2f, w.x, m3[0]);
                m3[1] = fmaf_(s2f, w.y, m3[1]);
                m3[2] = fmaf_(s2f, w.z, m3[2]);
                m3[3] = fmaf_(s2f, w.w, m3[3]);
            }
            int myPost = 0;
            #pragma unroll
            for (int a = 0; a < A_OUT; ++a) {
                float m = m3[a] + b3[a];
                bool sp = m > 1.0f;
                float s3f = sp ? 1.0f : 0.0f;
                m3[a] = m - s3f;
                ac[a] = ac[a] + s3f;
                int c = (int)__popcll(__ballot(sp));
                myPost = (lane == a) ? c : myPost;
            }
            if (lane < A_OUT) atomicAdd(&lds_post[t * A_OUT + lane], myPost);  // 2 duty waves
            if (t == T_STEPS - 1) {
                float r0 = ac[0] * 0.0625f, r1 = ac[1] * 0.0625f;
                float r2 = ac[2] * 0.0625f, r3 = ac[3] * 0.0625f;
                float mx = fmaxf(fmaxf(r0, r1), fmaxf(r2, r3));
                float e0 = expf(r0 - mx), e1 = expf(r1 - mx);
                float e2 = expf(r2 - mx), e3 = expf(r3 - mx);
                float s = ((e0 + e1) + e2) + e3;
                reinterpret_cast<float4*>(out)[blockIdx.x * EPB + el] =
                    make_float4(e0 / s, e1 / s, e2 / s, e3 / s);
            } else {
                #pragma unroll
                for (int a = 0; a < A_OUT; ++a) { m3acc[el][a] = m3[a]; m3acc[el][4 + a] = ac[a]; }
            }
        }
    }

    __syncthreads();
    for (int i = tid; i < T_STEPS * H; i += 512) atomicAdd(&g_pre[i], lds_pre[i]);
    if (tid < T_STEPS * A_OUT) atomicAdd(&g_post[tid], lds_post[tid]);
}

// elig_t = 0.95*elig_{t-1} + (A_PLUS-A_MINUS) * outer(post_t, pre_t); exact counts/B.
__global__ void snn_elig(const int* __restrict__ g_pre, const int* __restrict__ g_post,
                         const float* __restrict__ elig0, float* __restrict__ out) {
#pragma clang fp contract(off)
    int i = threadIdx.x;                 // 256 = A_OUT * H
    int a = i >> 6, h = i & 63;
    float e = elig0[i];
    const float invB = 1.0f / 65536.0f;
    for (int t = 0; t < T_STEPS; ++t) {
        float pre  = (float)g_pre[t * H + h] * invB;
        float post = (float)g_post[t * A_OUT + a] * invB;
        e = 0.95f * e + (-0.002f) * (post * pre);
    }
    out[NB * A_OUT + i] = e;
}

extern "C" void kernel_launch(void* const* d_in, const int* in_sizes, int n_in,
                              void* d_out, int out_size, void* d_ws, size_t ws_size,
                              hipStream_t stream) {
    const float* x     = (const float*)d_in[0];
    const float* W1    = (const float*)d_in[1];
    const float* b1    = (const float*)d_in[2];
    const float* W2    = (const float*)d_in[3];
    const float* b2    = (const float*)d_in[4];
    const float* W3    = (const float*)d_in[5];
    const float* b3    = (const float*)d_in[6];
    const float* elig0 = (const float*)d_in[7];
    float* out = (float*)d_out;

    char* ws = (char*)d_ws;
    int*   g_pre  = (int*)(ws);                    // 1024 ints
    int*   g_post = (int*)(ws + 4096);             // 64 ints
    float* W2T    = (float*)(ws + 8192);           // 4096 floats
    float* W3T    = (float*)(ws + 8192 + 16384);   // 256 floats

    (void)hipMemsetAsync(ws, 0, 4096 + 256, stream);  // zero count accumulators every launch
    snn_prep<<<17, 256, 0, stream>>>(W2, W3, W2T, W3T);
    snn_main<<<NB / EPB, 512, 0, stream>>>(x, W1, b1, W2T, b2, W3T, b3, out, g_pre, g_post);
    snn_elig<<<1, 256, 0, stream>>>(g_pre, g_post, elig0, out);
}